// Round 8
// baseline (997.153 us; speedup 1.0000x reference)
//
#include <hip/hip_runtime.h>

#define N_NODES 100000
#define N_EDGES 500000
#define H 128
#define EPS 1e-5f
#define NT_E 1954   // ceil(500000/256)
#define NT_N 391    // ceil(100000/256)
#define PGRID 256

typedef __attribute__((ext_vector_type(8))) short bf16x8;
typedef __attribute__((ext_vector_type(4))) float f32x4;

__device__ __forceinline__ unsigned short f2bf(float f) {
  unsigned int u = __builtin_bit_cast(unsigned int, f);
  u += 0x7FFFu + ((u >> 16) & 1u);
  return (unsigned short)(u >> 16);
}
__device__ __forceinline__ float bf2f(unsigned short u) {
  return __builtin_bit_cast(float, (unsigned)u << 16);
}

// XOR-swizzled LDS layout for [R x 128] bf16 tiles.
// (r,k) -> ushort idx r*128 + (k ^ ((r&7)<<3)); 16B chunks stay intact.
__device__ __forceinline__ int swz(int r, int k) {
  return r * 128 + (k ^ ((r & 7) << 3));
}

union PK8 { unsigned short u[8]; uint4 q; };

#define GLDS16(g, l)                                                        \
  __builtin_amdgcn_global_load_lds(                                         \
      (const __attribute__((address_space(1))) void*)(g),                   \
      (__attribute__((address_space(3))) void*)(l), 16, 0, 0)

// acc[8] += A(regs)[16 x 128] @ W(LDS)[128 -> 128]
__device__ __forceinline__ void gemm_regA(const bf16x8 a[4], const unsigned short* Wb,
                                          int m0, int kq, f32x4 acc[8]) {
  __builtin_amdgcn_s_setprio(1);
  #pragma unroll
  for (int kk = 0; kk < 4; ++kk) {
    const int k0 = kk * 32 + kq * 8;
    #pragma unroll
    for (int tc = 0; tc < 8; ++tc) {
      bf16x8 b = *(const bf16x8*)&Wb[swz(tc * 16 + m0, k0)];
      acc[tc] = __builtin_amdgcn_mfma_f32_16x16x32_bf16(a[kk], b, acc[tc], 0, 0, 0);
    }
  }
  __builtin_amdgcn_s_setprio(0);
}

// acc[8] += A(LDS rows wrow..wrow+16) @ W(LDS)
__device__ __forceinline__ void gemm_ldsA(const unsigned short* Hb, int wrow,
                                          const unsigned short* Wb,
                                          int m0, int kq, f32x4 acc[8]) {
  __builtin_amdgcn_s_setprio(1);
  #pragma unroll
  for (int kk = 0; kk < 4; ++kk) {
    const int k0 = kk * 32 + kq * 8;
    bf16x8 a = *(const bf16x8*)&Hb[swz(wrow + m0, k0)];
    #pragma unroll
    for (int tc = 0; tc < 8; ++tc) {
      bf16x8 b = *(const bf16x8*)&Wb[swz(tc * 16 + m0, k0)];
      acc[tc] = __builtin_amdgcn_mfma_f32_16x16x32_bf16(a, b, acc[tc], 0, 0, 0);
    }
  }
  __builtin_amdgcn_s_setprio(0);
}

__device__ __forceinline__ void zero_acc(f32x4 acc[8]) {
  #pragma unroll
  for (int b = 0; b < 8; ++b) acc[b] = (f32x4){0.f, 0.f, 0.f, 0.f};
}

__device__ __forceinline__ void ln4(const f32x4 acc[8], float mu[4], float rv[4]) {
  float s[4] = {0, 0, 0, 0}, ss[4] = {0, 0, 0, 0};
  #pragma unroll
  for (int tc = 0; tc < 8; ++tc)
    #pragma unroll
    for (int i = 0; i < 4; ++i) {
      const float v = acc[tc][i];
      s[i] += v;
      ss[i] += v * v;
    }
  #pragma unroll
  for (int off = 1; off < 16; off <<= 1)
    #pragma unroll
    for (int i = 0; i < 4; ++i) {
      s[i] += __shfl_xor(s[i], off);
      ss[i] += __shfl_xor(ss[i], off);
    }
  #pragma unroll
  for (int i = 0; i < 4; ++i) {
    const float m = s[i] * (1.0f / 128.0f);
    const float var = ss[i] * (1.0f / 128.0f) - m * m;
    mu[i] = m;
    rv[i] = rsqrtf(var + EPS);
  }
}

// ---------------- weight images ----------------

struct WSrc { const float* p[9]; };

// Pre-swizzled LDS image: wimg[m*16384 + swz(n,k)] = W_m[k][n] (bf16)
__global__ void wprep_kernel(WSrc wsrc, unsigned short* __restrict__ wimg) {
  const int id = blockIdx.x * 256 + threadIdx.x;  // 9*16384
  const int m = id >> 14;
  const int r = id & 16383;
  const int n = r & 127;
  const int k = r >> 7;
  wimg[m * 16384 + swz(n, k)] = f2bf(wsrc.p[m][k * 128 + n]);
}

// ---------------- px precompute: px_s = x@eW1a+eb1, px_r = x@eW1b, px_n = x@nW1a+nb1
// stored PERMUTED: px[node][m0*8+tc] = value for feature col tc*16+m0.

__global__ __launch_bounds__(512, 2) void px_kernel(
    const float* __restrict__ x, const unsigned short* __restrict__ wimg,
    const float* __restrict__ eb1, const float* __restrict__ nb1,
    unsigned short* __restrict__ pxs, unsigned short* __restrict__ pxr,
    unsigned short* __restrict__ pxn) {
  extern __shared__ unsigned short smem[];  // 3 * 16384 (96KB)
  const int t = threadIdx.x;
  #pragma unroll
  for (int j = 0; j < 12; ++j)
    GLDS16((const char*)wimg + j * 8192 + t * 16, (char*)smem + j * 8192 + t * 16);
  __syncthreads();

  const int lane = t & 63;
  const int wtile = (t >> 6) * 16;
  const int m0 = lane & 15;
  const int kq = lane >> 4;
  const long n0 = (long)blockIdx.x * 128;

  long an = n0 + wtile + m0;
  if (an > N_NODES - 1) an = N_NODES - 1;
  const float* px_ = x + an * H + kq * 8;
  bf16x8 aX[4];
  #pragma unroll
  for (int kk = 0; kk < 4; ++kk) {
    float4 v0 = *(const float4*)(px_ + kk * 32);
    float4 v1 = *(const float4*)(px_ + kk * 32 + 4);
    PK8 pk;
    pk.u[0] = f2bf(v0.x); pk.u[1] = f2bf(v0.y);
    pk.u[2] = f2bf(v0.z); pk.u[3] = f2bf(v0.w);
    pk.u[4] = f2bf(v1.x); pk.u[5] = f2bf(v1.y);
    pk.u[6] = f2bf(v1.z); pk.u[7] = f2bf(v1.w);
    aX[kk] = __builtin_bit_cast(bf16x8, pk.q);
  }
  const long cb = n0 + wtile + kq * 4;

  f32x4 acc[8];
  float bv[8];
  // px_s
  zero_acc(acc);
  gemm_regA(aX, smem, m0, kq, acc);
  #pragma unroll
  for (int tc = 0; tc < 8; ++tc) bv[tc] = eb1[tc * 16 + m0];
  #pragma unroll
  for (int i = 0; i < 4; ++i) {
    const long nn = cb + i;
    if (nn < N_NODES) {
      PK8 pk;
      #pragma unroll
      for (int tc = 0; tc < 8; ++tc) pk.u[tc] = f2bf(acc[tc][i] + bv[tc]);
      *(uint4*)(pxs + nn * H + m0 * 8) = pk.q;
    }
  }
  // px_r
  zero_acc(acc);
  gemm_regA(aX, smem + 16384, m0, kq, acc);
  #pragma unroll
  for (int i = 0; i < 4; ++i) {
    const long nn = cb + i;
    if (nn < N_NODES) {
      PK8 pk;
      #pragma unroll
      for (int tc = 0; tc < 8; ++tc) pk.u[tc] = f2bf(acc[tc][i]);
      *(uint4*)(pxr + nn * H + m0 * 8) = pk.q;
    }
  }
  // px_n
  zero_acc(acc);
  gemm_regA(aX, smem + 32768, m0, kq, acc);
  #pragma unroll
  for (int tc = 0; tc < 8; ++tc) bv[tc] = nb1[tc * 16 + m0];
  #pragma unroll
  for (int i = 0; i < 4; ++i) {
    const long nn = cb + i;
    if (nn < N_NODES) {
      PK8 pk;
      #pragma unroll
      for (int tc = 0; tc < 8; ++tc) pk.u[tc] = f2bf(acc[tc][i] + bv[tc]);
      *(uint4*)(pxn + nn * H + m0 * 8) = pk.q;
    }
  }
}

// ---------------- CSR build ----------------

__global__ void hist_kernel(const int* __restrict__ ridx, unsigned* __restrict__ cnt) {
  const int e = blockIdx.x * 256 + threadIdx.x;
  if (e < N_EDGES) atomicAdd(&cnt[ridx[e]], 1u);
}

__global__ void scan1_kernel(const unsigned* __restrict__ cnt,
                             unsigned* __restrict__ offs,
                             unsigned* __restrict__ part) {
  __shared__ unsigned sh[256];
  const int t = threadIdx.x;
  const int base = blockIdx.x * 1024 + t * 4;
  unsigned v[4];
  #pragma unroll
  for (int i = 0; i < 4; ++i) v[i] = (base + i < N_NODES) ? cnt[base + i] : 0u;
  unsigned pre[4];
  pre[0] = 0; pre[1] = v[0]; pre[2] = v[0] + v[1]; pre[3] = pre[2] + v[2];
  const unsigned tot = pre[3] + v[3];
  sh[t] = tot;
  __syncthreads();
  for (int d = 1; d < 256; d <<= 1) {
    const unsigned u_ = (t >= d) ? sh[t - d] : 0u;
    __syncthreads();
    sh[t] += u_;
    __syncthreads();
  }
  const unsigned excl = sh[t] - tot;
  #pragma unroll
  for (int i = 0; i < 4; ++i)
    if (base + i < N_NODES) offs[base + i] = excl + pre[i];
  if (t == 255) part[blockIdx.x] = sh[255];
}

__global__ void scan2_kernel(unsigned* __restrict__ part, int n) {
  __shared__ unsigned sh[128];
  const int t = threadIdx.x;
  const unsigned v = (t < n) ? part[t] : 0u;
  sh[t] = v;
  __syncthreads();
  for (int d = 1; d < 128; d <<= 1) {
    const unsigned u_ = (t >= d) ? sh[t - d] : 0u;
    __syncthreads();
    sh[t] += u_;
    __syncthreads();
  }
  if (t < n) part[t] = sh[t] - v;
}

__global__ void scan3_kernel(unsigned* __restrict__ offs,
                             const unsigned* __restrict__ part,
                             unsigned* __restrict__ cursor) {
  const int i = blockIdx.x * 256 + threadIdx.x;
  if (i < N_NODES) {
    const unsigned o = offs[i] + part[i >> 10];
    offs[i] = o;
    cursor[i] = o;
  }
  if (i == 0) offs[N_NODES] = N_EDGES;
}

__global__ void scatter_kernel(const int* __restrict__ ridx,
                               unsigned* __restrict__ cursor,
                               int* __restrict__ slot) {
  const int e = blockIdx.x * 256 + threadIdx.x;
  if (e < N_EDGES) slot[e] = (int)atomicAdd(&cursor[ridx[e]], 1u);
}

// ---------------- main kernels ----------------
// Persistent blocks; weights resident in LDS; h1/h2 handoffs wave-local
// (each wave owns rows [wtile, wtile+16) of Hb) => NO barriers in tile loop.
// Software-pipelined: next-tile idx + edge_attr loads issue under GEMM2/3.
// Epilogue: ea kept in regs; y and sum bounced through wave-private Hb rows;
// fully coalesced wave-level stores (no RMW, no re-read).

__global__ __launch_bounds__(1024, 4) void edge_kernel(
    const float* __restrict__ edge_attr, const int* __restrict__ eidx,
    const int* __restrict__ slot, const unsigned short* __restrict__ wimg,
    const unsigned short* __restrict__ pxs, const unsigned short* __restrict__ pxr,
    const float* __restrict__ eb2, const float* __restrict__ eb3,
    const float* __restrict__ eg, const float* __restrict__ ebeta,
    float* __restrict__ out_e, unsigned short* __restrict__ enew) {
  extern __shared__ unsigned short smem[];  // W1c|W2|W3 (96KB) + Hb (64KB)
  unsigned short* Wc = smem;
  unsigned short* W2 = smem + 16384;
  unsigned short* W3 = smem + 32768;
  unsigned short* Hb = smem + 49152;
  const int t = threadIdx.x;
  #pragma unroll
  for (int j = 0; j < 6; ++j)
    GLDS16((const char*)(wimg + 3 * 16384) + j * 16384 + t * 16,
           (char*)smem + j * 16384 + t * 16);
  __syncthreads();

  const int lane = t & 63;
  const int wtile = (t >> 6) * 16;
  const int m0 = lane & 15;
  const int kq = lane >> 4;
  const int* sidx = eidx;
  const int* ridx = eidx + N_EDGES;

  float b2v[8], b3v[8], gv[8], btv[8];
  #pragma unroll
  for (int tc = 0; tc < 8; ++tc) {
    const int col = tc * 16 + m0;
    b2v[tc] = eb2[col];
    b3v[tc] = eb3[col];
    gv[tc] = eg[col];
    btv[tc] = ebeta[col];
  }

  int tile = blockIdx.x;
  long cbN, cblN;
  int4 s4N, r4N;
  float4 efN[8];

#define EPRELOAD(T)                                                          \
  {                                                                          \
    const long e0_ = (long)(T) * 256;                                        \
    cbN = e0_ + wtile + kq * 4;                                              \
    cblN = cbN > (long)(N_EDGES - 4) ? (long)(N_EDGES - 4) : cbN;            \
    s4N = *(const int4*)&sidx[cblN];                                         \
    r4N = *(const int4*)&ridx[cblN];                                         \
    long ae_ = e0_ + wtile + m0;                                             \
    if (ae_ > N_EDGES - 1) ae_ = N_EDGES - 1;                                \
    const float* pe_ = edge_attr + ae_ * H + kq * 8;                         \
    _Pragma("unroll") for (int kk = 0; kk < 4; ++kk) {                       \
      efN[2 * kk] = *(const float4*)(pe_ + kk * 32);                         \
      efN[2 * kk + 1] = *(const float4*)(pe_ + kk * 32 + 4);                 \
    }                                                                        \
  }

  EPRELOAD(tile);

  for (;;) {
    const long e0_c = (long)tile * 256;
    const int* sp = (const int*)&s4N;
    const int* rp = (const int*)&r4N;

    // issue px gathers for this tile (complete under GEMM1)
    uint4 qs[4], qr[4];
    #pragma unroll
    for (int i = 0; i < 4; ++i) {
      qs[i] = *(const uint4*)(pxs + (long)sp[i] * H + m0 * 8);
      qr[i] = *(const uint4*)(pxr + (long)rp[i] * H + m0 * 8);
    }

    // convert staged f32 edge_attr -> bf16 A fragments
    bf16x8 aE[4];
    #pragma unroll
    for (int kk = 0; kk < 4; ++kk) {
      PK8 pk;
      const float* v0 = (const float*)&efN[2 * kk];
      const float* v1 = (const float*)&efN[2 * kk + 1];
      #pragma unroll
      for (int j = 0; j < 4; ++j) { pk.u[j] = f2bf(v0[j]); pk.u[4 + j] = f2bf(v1[j]); }
      aE[kk] = __builtin_bit_cast(bf16x8, pk.q);
    }

    // bounce edge_attr bf16 through wave-private Hb rows (epilogue transpose)
    #pragma unroll
    for (int kk = 0; kk < 4; ++kk)
      *(uint4*)&Hb[swz(wtile + m0, kq * 8 + kk * 32)] = __builtin_bit_cast(uint4, aE[kk]);

    f32x4 acc[8];
    zero_acc(acc);
    gemm_regA(aE, Wc, m0, kq, acc);

    // extract epilogue-layout edge_attr (C-layout) before h1 overwrites Hb
    unsigned eap_[16];
    #pragma unroll
    for (int i = 0; i < 4; ++i) {
      const int r_ = wtile + kq * 4 + i;
      #pragma unroll
      for (int t2 = 0; t2 < 4; ++t2) {
        unsigned lo = Hb[swz(r_, (2 * t2) * 16 + m0)];
        unsigned hi = Hb[swz(r_, (2 * t2 + 1) * 16 + m0)];
        eap_[i * 4 + t2] = lo | (hi << 16);
      }
    }

    // add gathered px_s + px_r (bias folded into pxs)
    #pragma unroll
    for (int i = 0; i < 4; ++i) {
      const unsigned short* us = (const unsigned short*)&qs[i];
      const unsigned short* ur = (const unsigned short*)&qr[i];
      #pragma unroll
      for (int tc = 0; tc < 8; ++tc)
        acc[tc][i] += bf2f(us[tc]) + bf2f(ur[tc]);
    }
    // h1 -> wave-local Hb rows
    #pragma unroll
    for (int tc = 0; tc < 8; ++tc) {
      const int col = tc * 16 + m0;
      #pragma unroll
      for (int i = 0; i < 4; ++i)
        Hb[swz(wtile + kq * 4 + i, col)] = f2bf(fmaxf(acc[tc][i], 0.f));
    }

    // prefetch next tile under GEMM2/h2/GEMM3
    const int nt = tile + PGRID;
    const bool more = nt < NT_E;
    if (more) EPRELOAD(nt);

    zero_acc(acc);
    gemm_ldsA(Hb, wtile, W2, m0, kq, acc);
    #pragma unroll
    for (int tc = 0; tc < 8; ++tc) {
      const int col = tc * 16 + m0;
      #pragma unroll
      for (int i = 0; i < 4; ++i)
        Hb[swz(wtile + kq * 4 + i, col)] = f2bf(fmaxf(acc[tc][i] + b2v[tc], 0.f));
    }
    zero_acc(acc);
    gemm_ldsA(Hb, wtile, W3, m0, kq, acc);

    #pragma unroll
    for (int tc = 0; tc < 8; ++tc)
      #pragma unroll
      for (int i = 0; i < 4; ++i) acc[tc][i] += b3v[tc];
    float mu[4], rv[4];
    ln4(acc, mu, rv);

    // ---- Pass A: y -> Hb -> coalesced enew store (CSR slot rows) ----
    #pragma unroll
    for (int tc = 0; tc < 8; ++tc) {
      const int col = tc * 16 + m0;
      #pragma unroll
      for (int i = 0; i < 4; ++i) {
        const float y = (acc[tc][i] - mu[i]) * rv[i] * gv[tc] + btv[tc];
        acc[tc][i] = y;  // keep for pass B
        Hb[swz(wtile + kq * 4 + i, col)] = f2bf(y);
      }
    }
    {
      const int r2 = wtile + (lane >> 2);
      const int c0 = (lane & 3) * 32;
      const long e = e0_c + r2;
      uint4 q0 = *(const uint4*)&Hb[swz(r2, c0)];
      uint4 q1 = *(const uint4*)&Hb[swz(r2, c0 + 8)];
      uint4 q2 = *(const uint4*)&Hb[swz(r2, c0 + 16)];
      uint4 q3 = *(const uint4*)&Hb[swz(r2, c0 + 24)];
      if (e < N_EDGES) {
        const long sv = slot[e];
        unsigned short* en = enew + sv * H + c0;
        *(uint4*)(en) = q0;
        *(uint4*)(en + 8) = q1;
        *(uint4*)(en + 16) = q2;
        *(uint4*)(en + 24) = q3;
      }
    }

    // ---- Pass B: sum = bf16(ea) + y -> Hb -> coalesced f32 out_e store ----
    #pragma unroll
    for (int i = 0; i < 4; ++i) {
      const int r_ = wtile + kq * 4 + i;
      #pragma unroll
      for (int t2 = 0; t2 < 4; ++t2) {
        const unsigned w_ = eap_[i * 4 + t2];
        const float sA = bf2f((unsigned short)(w_ & 0xffffu)) + acc[2 * t2][i];
        const float sB = bf2f((unsigned short)(w_ >> 16)) + acc[2 * t2 + 1][i];
        Hb[swz(r_, (2 * t2) * 16 + m0)] = f2bf(sA);
        Hb[swz(r_, (2 * t2 + 1) * 16 + m0)] = f2bf(sB);
      }
    }
    {
      const int r2 = wtile + (lane >> 2);
      const int c0 = (lane & 3) * 32;
      const long e = e0_c + r2;
      if (e < N_EDGES) {
        float* oe = out_e + e * (long)H + c0;
        #pragma unroll
        for (int c2 = 0; c2 < 4; ++c2) {
          uint4 qv = *(const uint4*)&Hb[swz(r2, c0 + c2 * 8)];
          const unsigned short* pu = (const unsigned short*)&qv;
          float4 o0, o1;
          o0.x = bf2f(pu[0]); o0.y = bf2f(pu[1]);
          o0.z = bf2f(pu[2]); o0.w = bf2f(pu[3]);
          o1.x = bf2f(pu[4]); o1.y = bf2f(pu[5]);
          o1.z = bf2f(pu[6]); o1.w = bf2f(pu[7]);
          *(float4*)(oe + c2 * 8) = o0;
          *(float4*)(oe + c2 * 8 + 4) = o1;
        }
      }
    }

    if (!more) break;
    tile = nt;
  }
#undef EPRELOAD
}

__global__ __launch_bounds__(1024, 4) void node_kernel(
    const float* __restrict__ x, const unsigned short* __restrict__ enew,
    const unsigned* __restrict__ offs, const unsigned short* __restrict__ wimg,
    const unsigned short* __restrict__ pxn,
    const float* __restrict__ nb2, const float* __restrict__ nb3,
    const float* __restrict__ ng, const float* __restrict__ nbeta,
    float* __restrict__ out_x) {
  extern __shared__ unsigned short smem[];  // nW1b|nW2|nW3 (96KB) + Hb (64KB)
  unsigned short* W1 = smem;
  unsigned short* W2 = smem + 16384;
  unsigned short* W3 = smem + 32768;
  unsigned short* Hb = smem + 49152;
  const int t = threadIdx.x;
  #pragma unroll
  for (int j = 0; j < 6; ++j)
    GLDS16((const char*)(wimg + 6 * 16384) + j * 16384 + t * 16,
           (char*)smem + j * 16384 + t * 16);
  __syncthreads();

  const int lane = t & 63;
  const int wtile = (t >> 6) * 16;
  const int m0 = lane & 15;
  const int kq = lane >> 4;

  float b2v[8], b3v[8], gv[8], btv[8];
  #pragma unroll
  for (int tc = 0; tc < 8; ++tc) {
    const int col = tc * 16 + m0;
    b2v[tc] = nb2[col];
    b3v[tc] = nb3[col];
    gv[tc] = ng[col];
    btv[tc] = nbeta[col];
  }

  for (int tile = blockIdx.x; tile < NT_N; tile += PGRID) {
    const long n0 = (long)tile * 256;
    long an = n0 + wtile + m0;
    if (an > N_NODES - 1) an = N_NODES - 1;
    const unsigned o0 = offs[an], o1 = offs[an + 1];

    // agg A-fragments: CSR rows are contiguous in enew (CSR-ordered store)
    float sm[4][8];
    #pragma unroll
    for (int kk = 0; kk < 4; ++kk)
      #pragma unroll
      for (int c = 0; c < 8; ++c) sm[kk][c] = 0.f;
    for (unsigned j = o0; j < o1; ++j) {
      const unsigned short* er = enew + (long)j * H + kq * 8;
      #pragma unroll
      for (int kk = 0; kk < 4; ++kk) {
        uint4 q = *(const uint4*)(er + kk * 32);
        const unsigned short* pu = (const unsigned short*)&q;
        #pragma unroll
        for (int c = 0; c < 8; ++c) sm[kk][c] += bf2f(pu[c]);
      }
    }
    bf16x8 aG[4];
    #pragma unroll
    for (int kk = 0; kk < 4; ++kk) {
      PK8 pk;
      #pragma unroll
      for (int c = 0; c < 8; ++c) pk.u[c] = f2bf(sm[kk][c]);
      aG[kk] = __builtin_bit_cast(bf16x8, pk.q);
    }

    const long cb = n0 + wtile + kq * 4;
    const long cbl = cb > (long)(N_NODES - 4) ? (long)(N_NODES - 4) : cb;
    uint4 qn[4];
    #pragma unroll
    for (int i = 0; i < 4; ++i)
      qn[i] = *(const uint4*)(pxn + (cbl + i) * H + m0 * 8);

    f32x4 acc[8];
    zero_acc(acc);
    gemm_regA(aG, W1, m0, kq, acc);
    #pragma unroll
    for (int i = 0; i < 4; ++i) {
      const unsigned short* un = (const unsigned short*)&qn[i];
      #pragma unroll
      for (int tc = 0; tc < 8; ++tc) acc[tc][i] += bf2f(un[tc]);
    }
    #pragma unroll
    for (int tc = 0; tc < 8; ++tc) {
      const int col = tc * 16 + m0;
      #pragma unroll
      for (int i = 0; i < 4; ++i)
        Hb[swz(wtile + kq * 4 + i, col)] = f2bf(fmaxf(acc[tc][i], 0.f));
    }
    zero_acc(acc);
    gemm_ldsA(Hb, wtile, W2, m0, kq, acc);
    #pragma unroll
    for (int tc = 0; tc < 8; ++tc) {
      const int col = tc * 16 + m0;
      #pragma unroll
      for (int i = 0; i < 4; ++i)
        Hb[swz(wtile + kq * 4 + i, col)] = f2bf(fmaxf(acc[tc][i] + b2v[tc], 0.f));
    }
    zero_acc(acc);
    gemm_ldsA(Hb, wtile, W3, m0, kq, acc);

    #pragma unroll
    for (int tc = 0; tc < 8; ++tc)
      #pragma unroll
      for (int i = 0; i < 4; ++i) acc[tc][i] += b3v[tc];
    float mu[4], rv[4];
    ln4(acc, mu, rv);

    #pragma unroll
    for (int i = 0; i < 4; ++i) {
      const long nn = cb + i;
      if (nn < N_NODES) {
        #pragma unroll
        for (int tc = 0; tc < 8; ++tc) {
          const int col = tc * 16 + m0;
          const float y = (acc[tc][i] - mu[i]) * rv[i] * gv[tc] + btv[tc];
          out_x[nn * H + col] = x[nn * H + col] + y;
        }
      }
    }
  }
}

extern "C" void kernel_launch(void* const* d_in, const int* in_sizes, int n_in,
                              void* d_out, int out_size, void* d_ws, size_t ws_size,
                              hipStream_t stream) {
  (void)in_sizes; (void)n_in; (void)out_size; (void)ws_size;
  const float* x         = (const float*)d_in[0];
  const float* edge_attr = (const float*)d_in[1];
  const int*   eidx      = (const int*)d_in[2];
  const float* eW1 = (const float*)d_in[3];
  const float* eb1 = (const float*)d_in[4];
  const float* eW2 = (const float*)d_in[5];
  const float* eb2 = (const float*)d_in[6];
  const float* eW3 = (const float*)d_in[7];
  const float* eb3 = (const float*)d_in[8];
  const float* eg  = (const float*)d_in[9];
  const float* ebt = (const float*)d_in[10];
  const float* nW1 = (const float*)d_in[11];
  const float* nb1 = (const float*)d_in[12];
  const float* nW2 = (const float*)d_in[13];
  const float* nb2 = (const float*)d_in[14];
  const float* nW3 = (const float*)d_in[15];
  const float* nb3 = (const float*)d_in[16];
  const float* ng  = (const float*)d_in[17];
  const float* nbt = (const float*)d_in[18];

  float* out_x = (float*)d_out;                        // N_NODES*H
  float* out_e = (float*)d_out + (size_t)N_NODES * H;  // N_EDGES*H

  // ws layout (bytes)
  char* w = (char*)d_ws;
  unsigned short* enew = (unsigned short*)(w + 0);            // 128,000,000
  unsigned short* pxs  = (unsigned short*)(w + 128000000);    //  25,600,000
  unsigned short* pxr  = (unsigned short*)(w + 153600000);    //  25,600,000
  unsigned short* pxn  = (unsigned short*)(w + 179200000);    //  25,600,000
  unsigned short* wimg = (unsigned short*)(w + 204800000);    //     294,912
  unsigned* offs   = (unsigned*)(w + 205094912);              //     400,128
  unsigned* cnt    = (unsigned*)(w + 205495040);              //     400,128
  unsigned* cursor = (unsigned*)(w + 205895168);              //     400,128
  unsigned* part   = (unsigned*)(w + 206295296);              //       1,024
  int* slot        = (int*)(w + 206296320);                   //   2,000,000
  // total ~208.3 MB

  const int* ridx = eidx + N_EDGES;

  hipFuncSetAttribute((const void*)px_kernel,
                      hipFuncAttributeMaxDynamicSharedMemorySize, 98304);
  hipFuncSetAttribute((const void*)edge_kernel,
                      hipFuncAttributeMaxDynamicSharedMemorySize, 163840);
  hipFuncSetAttribute((const void*)node_kernel,
                      hipFuncAttributeMaxDynamicSharedMemorySize, 163840);

  hipMemsetAsync(cnt, 0, (size_t)N_NODES * sizeof(unsigned), stream);

  WSrc wsrc;
  wsrc.p[0] = eW1;                 // eW1a (senders)
  wsrc.p[1] = eW1 + 16384;         // eW1b (receivers)
  wsrc.p[2] = nW1;                 // nW1a (x)
  wsrc.p[3] = eW1 + 32768;         // eW1c (edge_attr)
  wsrc.p[4] = eW2;
  wsrc.p[5] = eW3;
  wsrc.p[6] = nW1 + 16384;         // nW1b (agg)
  wsrc.p[7] = nW2;
  wsrc.p[8] = nW3;
  wprep_kernel<<<576, 256, 0, stream>>>(wsrc, wimg);

  px_kernel<<<(N_NODES + 127) / 128, 512, 98304, stream>>>(x, wimg, eb1, nb1,
                                                           pxs, pxr, pxn);

  hist_kernel<<<(N_EDGES + 255) / 256, 256, 0, stream>>>(ridx, cnt);
  scan1_kernel<<<(N_NODES + 1023) / 1024, 256, 0, stream>>>(cnt, offs, part);
  scan2_kernel<<<1, 128, 0, stream>>>(part, (N_NODES + 1023) / 1024);
  scan3_kernel<<<(N_NODES + 255) / 256, 256, 0, stream>>>(offs, part, cursor);
  scatter_kernel<<<(N_EDGES + 255) / 256, 256, 0, stream>>>(ridx, cursor, slot);

  edge_kernel<<<PGRID, 1024, 163840, stream>>>(edge_attr, eidx, slot, wimg,
                                               pxs, pxr, eb2, eb3, eg, ebt,
                                               out_e, enew);
  node_kernel<<<PGRID, 1024, 163840, stream>>>(x, enew, offs, wimg, pxn,
                                               nb2, nb3, ng, nbt, out_x);
}

// Round 9
// 540.146 us; speedup vs baseline: 1.8461x; 1.8461x over previous
//
#include <hip/hip_runtime.h>

#define N_NODES 100000
#define N_EDGES 500000
#define H 128
#define EPS 1e-5f

typedef __attribute__((ext_vector_type(8))) short bf16x8;
typedef __attribute__((ext_vector_type(4))) float f32x4;

__device__ __forceinline__ unsigned short f2bf(float f) {
  unsigned int u = __builtin_bit_cast(unsigned int, f);
  u += 0x7FFFu + ((u >> 16) & 1u);
  return (unsigned short)(u >> 16);
}
__device__ __forceinline__ float bf2f(unsigned short u) {
  return __builtin_bit_cast(float, (unsigned)u << 16);
}

// XOR-swizzled LDS layout for [R x 128] bf16 tiles.
// (r,k) -> ushort idx r*128 + (k ^ ((r&7)<<3)); 16B chunks stay intact.
__device__ __forceinline__ int swz(int r, int k) {
  return r * 128 + (k ^ ((r & 7) << 3));
}

union PK8 { unsigned short u[8]; uint4 q; };

#define GLDS16(g, l)                                                        \
  __builtin_amdgcn_global_load_lds(                                         \
      (const __attribute__((address_space(1))) void*)(g),                   \
      (__attribute__((address_space(3))) void*)(l), 16, 0, 0)

// Copy a 32KB pre-swizzled weight image into LDS (512 threads x 16B x 4).
__device__ __forceinline__ void stage_w512(unsigned short* dst,
                                           const unsigned short* img) {
  const int t = threadIdx.x;
  #pragma unroll
  for (int j = 0; j < 4; ++j)
    GLDS16((const char*)img + j * 8192 + t * 16, (char*)dst + j * 8192 + t * 16);
}

// Copy a 32KB pre-swizzled weight image into LDS (640 threads, predicated).
__device__ __forceinline__ void stage_w640(unsigned short* dst,
                                           const unsigned short* img) {
  const int t = threadIdx.x;
  #pragma unroll
  for (int j = 0; j < 4; ++j) {
    const int idx = j * 640 + t;
    if (idx < 2048)
      GLDS16((const char*)img + idx * 16, (char*)dst + idx * 16);
  }
}

// acc[8] += A(regs)[16 x 128] @ W(LDS)[128 -> 128]
__device__ __forceinline__ void gemm_regA(const bf16x8 a[4], const unsigned short* Wb,
                                          int m0, int kq, f32x4 acc[8]) {
  #pragma unroll
  for (int kk = 0; kk < 4; ++kk) {
    const int k0 = kk * 32 + kq * 8;
    #pragma unroll
    for (int tc = 0; tc < 8; ++tc) {
      bf16x8 b = *(const bf16x8*)&Wb[swz(tc * 16 + m0, k0)];
      acc[tc] = __builtin_amdgcn_mfma_f32_16x16x32_bf16(a[kk], b, acc[tc], 0, 0, 0);
    }
  }
}

// acc[8] += A(LDS rows wrow..wrow+16) @ W(LDS)
__device__ __forceinline__ void gemm_ldsA(const unsigned short* Hb, int wrow,
                                          const unsigned short* Wb,
                                          int m0, int kq, f32x4 acc[8]) {
  #pragma unroll
  for (int kk = 0; kk < 4; ++kk) {
    const int k0 = kk * 32 + kq * 8;
    bf16x8 a = *(const bf16x8*)&Hb[swz(wrow + m0, k0)];
    #pragma unroll
    for (int tc = 0; tc < 8; ++tc) {
      bf16x8 b = *(const bf16x8*)&Wb[swz(tc * 16 + m0, k0)];
      acc[tc] = __builtin_amdgcn_mfma_f32_16x16x32_bf16(a, b, acc[tc], 0, 0, 0);
    }
  }
}

__device__ __forceinline__ void zero_acc(f32x4 acc[8]) {
  #pragma unroll
  for (int b = 0; b < 8; ++b) acc[b] = (f32x4){0.f, 0.f, 0.f, 0.f};
}

// C-layout: col = tc*16 + (lane&15), row(within wave tile) = kq*4 + i
__device__ __forceinline__ void write_h(unsigned short* Hb, const f32x4 acc[8],
                                        const float* __restrict__ bias,
                                        int wrow, int m0, int kq) {
  #pragma unroll
  for (int tc = 0; tc < 8; ++tc) {
    const int col = tc * 16 + m0;
    const float b = bias[col];
    #pragma unroll
    for (int i = 0; i < 4; ++i)
      Hb[swz(wrow + kq * 4 + i, col)] = f2bf(fmaxf(acc[tc][i] + b, 0.0f));
  }
}

__device__ __forceinline__ void ln4(const f32x4 acc[8], float mu[4], float rv[4]) {
  float s[4] = {0, 0, 0, 0}, ss[4] = {0, 0, 0, 0};
  #pragma unroll
  for (int tc = 0; tc < 8; ++tc)
    #pragma unroll
    for (int i = 0; i < 4; ++i) {
      const float v = acc[tc][i];
      s[i] += v;
      ss[i] += v * v;
    }
  #pragma unroll
  for (int off = 1; off < 16; off <<= 1)
    #pragma unroll
    for (int i = 0; i < 4; ++i) {
      s[i] += __shfl_xor(s[i], off);
      ss[i] += __shfl_xor(ss[i], off);
    }
  #pragma unroll
  for (int i = 0; i < 4; ++i) {
    const float m = s[i] * (1.0f / 128.0f);
    const float var = ss[i] * (1.0f / 128.0f) - m * m;
    mu[i] = m;
    rv[i] = rsqrtf(var + EPS);
  }
}

// ---------------- prep kernels ----------------

__global__ void xprep_kernel(const float* __restrict__ x,
                             unsigned short* __restrict__ xb) {
  const long i = (long)blockIdx.x * 256 + threadIdx.x;
  const long base = i * 8;
  if (base < (long)N_NODES * H) {
    float4 v0 = *(const float4*)(x + base);
    float4 v1 = *(const float4*)(x + base + 4);
    PK8 pk;
    pk.u[0] = f2bf(v0.x); pk.u[1] = f2bf(v0.y);
    pk.u[2] = f2bf(v0.z); pk.u[3] = f2bf(v0.w);
    pk.u[4] = f2bf(v1.x); pk.u[5] = f2bf(v1.y);
    pk.u[6] = f2bf(v1.z); pk.u[7] = f2bf(v1.w);
    *(uint4*)(xb + base) = pk.q;
  }
}

struct WSrc { const float* p[9]; };

// Pre-swizzled LDS image: wimg[m*16384 + swz(n,k)] = W_m[k][n] (bf16)
__global__ void wprep_kernel(WSrc wsrc, unsigned short* __restrict__ wimg) {
  const int id = blockIdx.x * 256 + threadIdx.x;  // 9*16384
  const int m = id >> 14;
  const int r = id & 16383;
  const int n = r & 127;
  const int k = r >> 7;
  wimg[m * 16384 + swz(n, k)] = f2bf(wsrc.p[m][k * 128 + n]);
}

// ---------------- CSR build ----------------

__global__ void hist_kernel(const int* __restrict__ ridx, unsigned* __restrict__ cnt) {
  const int e = blockIdx.x * 256 + threadIdx.x;
  if (e < N_EDGES) atomicAdd(&cnt[ridx[e]], 1u);
}

__global__ void scan1_kernel(const unsigned* __restrict__ cnt,
                             unsigned* __restrict__ offs,
                             unsigned* __restrict__ part) {
  __shared__ unsigned sh[256];
  const int t = threadIdx.x;
  const int base = blockIdx.x * 1024 + t * 4;
  unsigned v[4];
  #pragma unroll
  for (int i = 0; i < 4; ++i) v[i] = (base + i < N_NODES) ? cnt[base + i] : 0u;
  unsigned pre[4];
  pre[0] = 0; pre[1] = v[0]; pre[2] = v[0] + v[1]; pre[3] = pre[2] + v[2];
  const unsigned tot = pre[3] + v[3];
  sh[t] = tot;
  __syncthreads();
  for (int d = 1; d < 256; d <<= 1) {
    const unsigned u_ = (t >= d) ? sh[t - d] : 0u;
    __syncthreads();
    sh[t] += u_;
    __syncthreads();
  }
  const unsigned excl = sh[t] - tot;
  #pragma unroll
  for (int i = 0; i < 4; ++i)
    if (base + i < N_NODES) offs[base + i] = excl + pre[i];
  if (t == 255) part[blockIdx.x] = sh[255];
}

__global__ void scan2_kernel(unsigned* __restrict__ part, int n) {
  __shared__ unsigned sh[128];
  const int t = threadIdx.x;
  const unsigned v = (t < n) ? part[t] : 0u;
  sh[t] = v;
  __syncthreads();
  for (int d = 1; d < 128; d <<= 1) {
    const unsigned u_ = (t >= d) ? sh[t - d] : 0u;
    __syncthreads();
    sh[t] += u_;
    __syncthreads();
  }
  if (t < n) part[t] = sh[t] - v;
}

__global__ void scan3_kernel(unsigned* __restrict__ offs,
                             const unsigned* __restrict__ part,
                             unsigned* __restrict__ cursor) {
  const int i = blockIdx.x * 256 + threadIdx.x;
  if (i < N_NODES) {
    const unsigned o = offs[i] + part[i >> 10];
    offs[i] = o;
    cursor[i] = o;
  }
  if (i == 0) offs[N_NODES] = N_EDGES;
}

__global__ void scatter_kernel(const int* __restrict__ ridx,
                               unsigned* __restrict__ cursor,
                               unsigned* __restrict__ eord) {
  const int e = blockIdx.x * 256 + threadIdx.x;
  if (e < N_EDGES) {
    const unsigned p = atomicAdd(&cursor[ridx[e]], 1u);
    eord[p] = (unsigned)e;
  }
}

// ---------------- main kernels ----------------
// Edge: BM=160, 640 threads (10 waves), LDS = Wbuf 32KB + Hbuf 40KB = 72KB
// -> 2 blocks/CU, 20 waves/CU. VGPR cap 102 (launch_bounds 640,5); round-4
// code measured 56 VGPR, so no spill expected.

__global__ __launch_bounds__(640, 5) void edge_kernel(
    const unsigned short* __restrict__ xb, const float* __restrict__ edge_attr,
    const int* __restrict__ eidx, const unsigned short* __restrict__ wimg,
    const float* __restrict__ eb1, const float* __restrict__ eb2,
    const float* __restrict__ eb3,
    const float* __restrict__ eg, const float* __restrict__ ebeta,
    float* __restrict__ out_e, unsigned short* __restrict__ enew) {
  extern __shared__ unsigned short smem[];
  unsigned short* Wbuf = smem;           // 16384 ushorts (32KB)
  unsigned short* Hbuf = smem + 16384;   // 20480 ushorts (40KB, 160 rows)

  const int t = threadIdx.x;
  const int lane = t & 63;
  const int wave = t >> 6;        // 0..9
  const int wrow = wave * 16;     // 0..144
  const int m0 = lane & 15;
  const int kq = lane >> 4;
  const long e0 = (long)blockIdx.x * 160;
  const int* sidx = eidx;
  const int* ridx = eidx + N_EDGES;

  // t0: stage W1a->Wbuf, W1b->Hbuf (Hbuf free during layer 1)
  stage_w640(Wbuf, wimg + 0L * 16384);
  stage_w640(Hbuf, wimg + 1L * 16384);

  // t0: gather A fragments straight to registers
  long erow = e0 + wrow + m0;
  if (erow > N_EDGES - 1) erow = N_EDGES - 1;
  const long ns = sidx[erow];
  const long nr = ridx[erow];
  bf16x8 aS[4], aR[4];
  {
    const unsigned short* ps = xb + ns * H + kq * 8;
    const unsigned short* pr = xb + nr * H + kq * 8;
    #pragma unroll
    for (int kk = 0; kk < 4; ++kk) {
      aS[kk] = *(const bf16x8*)(ps + kk * 32);
      aR[kk] = *(const bf16x8*)(pr + kk * 32);
    }
  }

  f32x4 acc[8];
  zero_acc(acc);

  __syncthreads();  // W1a, W1b staged
  gemm_regA(aS, Wbuf, m0, kq, acc);
  gemm_regA(aR, Hbuf, m0, kq, acc);

  // edge_attr fragments (f32 -> bf16), loads issued here, used after next sync
  bf16x8 aE[4];
  {
    const float* pe = edge_attr + erow * (long)H + kq * 8;
    #pragma unroll
    for (int kk = 0; kk < 4; ++kk) {
      float4 v0 = *(const float4*)(pe + kk * 32);
      float4 v1 = *(const float4*)(pe + kk * 32 + 4);
      PK8 pk;
      pk.u[0] = f2bf(v0.x); pk.u[1] = f2bf(v0.y);
      pk.u[2] = f2bf(v0.z); pk.u[3] = f2bf(v0.w);
      pk.u[4] = f2bf(v1.x); pk.u[5] = f2bf(v1.y);
      pk.u[6] = f2bf(v1.z); pk.u[7] = f2bf(v1.w);
      aE[kk] = __builtin_bit_cast(bf16x8, pk.q);
    }
  }

  __syncthreads();  // all waves done with Wbuf (W1a)
  stage_w640(Wbuf, wimg + 2L * 16384);  // W1c
  __syncthreads();
  gemm_regA(aE, Wbuf, m0, kq, acc);

  __syncthreads();  // Wbuf (W1c) consumed; Hbuf (W1b) long consumed
  stage_w640(Wbuf, wimg + 3L * 16384);  // W2
  write_h(Hbuf, acc, eb1, wrow, m0, kq);  // h1
  zero_acc(acc);
  __syncthreads();
  gemm_ldsA(Hbuf, wrow, Wbuf, m0, kq, acc);

  __syncthreads();
  stage_w640(Wbuf, wimg + 4L * 16384);  // W3
  write_h(Hbuf, acc, eb2, wrow, m0, kq);  // h2
  zero_acc(acc);
  __syncthreads();
  gemm_ldsA(Hbuf, wrow, Wbuf, m0, kq, acc);

  // ---- epilogue: +b3, LN ----
  float gm[8], bt[8];
  #pragma unroll
  for (int tc = 0; tc < 8; ++tc) {
    const int col = tc * 16 + m0;
    const float b3 = eb3[col];
    gm[tc] = eg[col];
    bt[tc] = ebeta[col];
    #pragma unroll
    for (int i = 0; i < 4; ++i) acc[tc][i] += b3;
  }
  float mu[4], rv[4];
  ln4(acc, mu, rv);

  __syncthreads();  // Hbuf (h2) consumed by all waves
  #pragma unroll
  for (int tc = 0; tc < 8; ++tc) {
    const int col = tc * 16 + m0;
    #pragma unroll
    for (int i = 0; i < 4; ++i) {
      const float y = (acc[tc][i] - mu[i]) * rv[i] * gm[tc] + bt[tc];
      Hbuf[swz(wrow + kq * 4 + i, col)] = f2bf(y);
    }
  }
  __syncthreads();

  // coalesced stores: 4 threads per row, 32 cols each (640 thr = 160 rows)
  {
    const int r = t >> 2;
    const int c0 = (t & 3) * 32;
    const long e = e0 + r;
    if (e < N_EDGES) {
      const float* ea = edge_attr + e * (long)H + c0;
      float* oe = out_e + e * (long)H + c0;
      unsigned short* en = enew + e * (long)H + c0;
      #pragma unroll
      for (int c2 = 0; c2 < 4; ++c2) {
        uint4 qv = *(const uint4*)&Hbuf[swz(r, c0 + c2 * 8)];
        *(uint4*)(en + c2 * 8) = qv;
        const unsigned short* pu = (const unsigned short*)&qv;
        float4 a0 = *(const float4*)(ea + c2 * 8);
        float4 a1 = *(const float4*)(ea + c2 * 8 + 4);
        float4 o0, o1;
        o0.x = a0.x + bf2f(pu[0]); o0.y = a0.y + bf2f(pu[1]);
        o0.z = a0.z + bf2f(pu[2]); o0.w = a0.w + bf2f(pu[3]);
        o1.x = a1.x + bf2f(pu[4]); o1.y = a1.y + bf2f(pu[5]);
        o1.z = a1.z + bf2f(pu[6]); o1.w = a1.w + bf2f(pu[7]);
        *(float4*)(oe + c2 * 8) = o0;
        *(float4*)(oe + c2 * 8 + 4) = o1;
      }
    }
  }
}

__global__ __launch_bounds__(512, 4) void node_kernel(
    const unsigned short* __restrict__ xb, const float* __restrict__ x,
    const unsigned short* __restrict__ enew,
    const unsigned* __restrict__ offs, const unsigned* __restrict__ eord,
    const unsigned short* __restrict__ wimg,
    const float* __restrict__ nb1, const float* __restrict__ nb2,
    const float* __restrict__ nb3,
    const float* __restrict__ ng, const float* __restrict__ nbeta,
    float* __restrict__ out_x) {
  __shared__ unsigned short Wbuf[128 * 128];
  __shared__ unsigned short Hbuf[128 * 128];

  const int t = threadIdx.x;
  const int lane = t & 63;
  const int wave = t >> 6;
  const int wrow = wave * 16;
  const int m0 = lane & 15;
  const int kq = lane >> 4;
  const long n0 = (long)blockIdx.x * 128;

  stage_w512(Wbuf, wimg + 5L * 16384);  // nW1a

  // x fragments to registers
  long nrow = n0 + wrow + m0;
  if (nrow > N_NODES - 1) nrow = N_NODES - 1;
  bf16x8 aX[4];
  {
    const unsigned short* px = xb + nrow * H + kq * 8;
    #pragma unroll
    for (int kk = 0; kk < 4; ++kk) aX[kk] = *(const bf16x8*)(px + kk * 32);
  }

  // CSR gather-sum: thread t owns (row t>>2, col quarter t&3)
  float av[32];
  #pragma unroll
  for (int i = 0; i < 32; ++i) av[i] = 0.f;
  {
    const long sn = n0 + (t >> 2);
    if (sn < N_NODES) {
      const unsigned o0 = offs[sn], o1 = offs[sn + 1];
      const int c0 = (t & 3) * 32;
      for (unsigned u_ = o0; u_ < o1; ++u_) {
        const unsigned short* er = enew + (long)eord[u_] * H + c0;
        #pragma unroll
        for (int c2 = 0; c2 < 4; ++c2) {
          uint4 qv = *(const uint4*)(er + c2 * 8);
          const unsigned short* pu = (const unsigned short*)&qv;
          #pragma unroll
          for (int j = 0; j < 8; ++j) av[c2 * 8 + j] += bf2f(pu[j]);
        }
      }
    }
  }

  f32x4 acc[8];
  zero_acc(acc);

  __syncthreads();  // Wbuf staged
  gemm_regA(aX, Wbuf, m0, kq, acc);
  __syncthreads();
  stage_w512(Wbuf, wimg + 6L * 16384);  // nW1b
  // av -> Hbuf (bf16, swizzled)
  {
    const int r = t >> 2;
    const int c0 = (t & 3) * 32;
    #pragma unroll
    for (int c2 = 0; c2 < 4; ++c2) {
      PK8 pk;
      #pragma unroll
      for (int j = 0; j < 8; ++j) pk.u[j] = f2bf(av[c2 * 8 + j]);
      *(uint4*)&Hbuf[swz(r, c0 + c2 * 8)] = pk.q;
    }
  }
  __syncthreads();
  gemm_ldsA(Hbuf, wrow, Wbuf, m0, kq, acc);  // acc += agg @ nW1b

  __syncthreads();
  stage_w512(Wbuf, wimg + 7L * 16384);  // nW2
  write_h(Hbuf, acc, nb1, wrow, m0, kq);
  zero_acc(acc);
  __syncthreads();
  gemm_ldsA(Hbuf, wrow, Wbuf, m0, kq, acc);

  __syncthreads();
  stage_w512(Wbuf, wimg + 8L * 16384);  // nW3
  write_h(Hbuf, acc, nb2, wrow, m0, kq);
  zero_acc(acc);
  __syncthreads();
  gemm_ldsA(Hbuf, wrow, Wbuf, m0, kq, acc);

  // epilogue
  float gm[8], bt[8];
  #pragma unroll
  for (int tc = 0; tc < 8; ++tc) {
    const int col = tc * 16 + m0;
    const float b3 = nb3[col];
    gm[tc] = ng[col];
    bt[tc] = nbeta[col];
    #pragma unroll
    for (int i = 0; i < 4; ++i) acc[tc][i] += b3;
  }
  float mu[4], rv[4];
  ln4(acc, mu, rv);

  __syncthreads();
  #pragma unroll
  for (int tc = 0; tc < 8; ++tc) {
    const int col = tc * 16 + m0;
    #pragma unroll
    for (int i = 0; i < 4; ++i) {
      const float y = (acc[tc][i] - mu[i]) * rv[i] * gm[tc] + bt[tc];
      Hbuf[swz(wrow + kq * 4 + i, col)] = f2bf(y);
    }
  }
  __syncthreads();

  {
    const int r = t >> 2;
    const int c0 = (t & 3) * 32;
    const long n = n0 + r;
    if (n < N_NODES) {
      const float* xr = x + n * (long)H + c0;
      float* ox = out_x + n * (long)H + c0;
      #pragma unroll
      for (int c2 = 0; c2 < 4; ++c2) {
        uint4 qv = *(const uint4*)&Hbuf[swz(r, c0 + c2 * 8)];
        const unsigned short* pu = (const unsigned short*)&qv;
        float4 a0 = *(const float4*)(xr + c2 * 8);
        float4 a1 = *(const float4*)(xr + c2 * 8 + 4);
        float4 o0, o1;
        o0.x = a0.x + bf2f(pu[0]); o0.y = a0.y + bf2f(pu[1]);
        o0.z = a0.z + bf2f(pu[2]); o0.w = a0.w + bf2f(pu[3]);
        o1.x = a1.x + bf2f(pu[4]); o1.y = a1.y + bf2f(pu[5]);
        o1.z = a1.z + bf2f(pu[6]); o1.w = a1.w + bf2f(pu[7]);
        *(float4*)(ox + c2 * 8) = o0;
        *(float4*)(ox + c2 * 8 + 4) = o1;
      }
    }
  }
}

extern "C" void kernel_launch(void* const* d_in, const int* in_sizes, int n_in,
                              void* d_out, int out_size, void* d_ws, size_t ws_size,
                              hipStream_t stream) {
  (void)in_sizes; (void)n_in; (void)out_size; (void)ws_size;
  const float* x         = (const float*)d_in[0];
  const float* edge_attr = (const float*)d_in[1];
  const int*   eidx      = (const int*)d_in[2];
  const float* eW1 = (const float*)d_in[3];
  const float* eb1 = (const float*)d_in[4];
  const float* eW2 = (const float*)d_in[5];
  const float* eb2 = (const float*)d_in[6];
  const float* eW3 = (const float*)d_in[7];
  const float* eb3 = (const float*)d_in[8];
  const float* eg  = (const float*)d_in[9];
  const float* ebt = (const float*)d_in[10];
  const float* nW1 = (const float*)d_in[11];
  const float* nb1 = (const float*)d_in[12];
  const float* nW2 = (const float*)d_in[13];
  const float* nb2 = (const float*)d_in[14];
  const float* nW3 = (const float*)d_in[15];
  const float* nb3 = (const float*)d_in[16];
  const float* ng  = (const float*)d_in[17];
  const float* nbt = (const float*)d_in[18];

  float* out_x = (float*)d_out;                        // N_NODES*H
  float* out_e = (float*)d_out + (size_t)N_NODES * H;  // N_EDGES*H

  // ws layout (bytes)
  char* w = (char*)d_ws;
  unsigned short* enew = (unsigned short*)(w + 0);            // 128,000,000
  unsigned short* xb   = (unsigned short*)(w + 128000000);    //  25,600,000
  unsigned short* wimg = (unsigned short*)(w + 153600000);    //     294,912
  unsigned* offs   = (unsigned*)(w + 153894912);              //     400,128
  unsigned* cnt    = (unsigned*)(w + 154295040);              //     400,128
  unsigned* cursor = (unsigned*)(w + 154695168);              //     400,128
  unsigned* part   = (unsigned*)(w + 155095296);              //       1,024
  unsigned* eord   = (unsigned*)(w + 155096320);              //   2,000,000
  // total ~157.1 MB

  const int* ridx = eidx + N_EDGES;

  hipFuncSetAttribute((const void*)edge_kernel,
                      hipFuncAttributeMaxDynamicSharedMemorySize, 73728);

  hipMemsetAsync(cnt, 0, (size_t)N_NODES * sizeof(unsigned), stream);

  WSrc wsrc;
  wsrc.p[0] = eW1;
  wsrc.p[1] = eW1 + 16384;
  wsrc.p[2] = eW1 + 32768;
  wsrc.p[3] = eW2;
  wsrc.p[4] = eW3;
  wsrc.p[5] = nW1;
  wsrc.p[6] = nW1 + 16384;
  wsrc.p[7] = nW2;
  wsrc.p[8] = nW3;

  xprep_kernel<<<(N_NODES * H / 8 + 255) / 256, 256, 0, stream>>>(x, xb);
  wprep_kernel<<<576, 256, 0, stream>>>(wsrc, wimg);

  hist_kernel<<<(N_EDGES + 255) / 256, 256, 0, stream>>>(ridx, cnt);
  scan1_kernel<<<(N_NODES + 1023) / 1024, 256, 0, stream>>>(cnt, offs, part);
  scan2_kernel<<<1, 128, 0, stream>>>(part, (N_NODES + 1023) / 1024);
  scan3_kernel<<<(N_NODES + 255) / 256, 256, 0, stream>>>(offs, part, cursor);
  scatter_kernel<<<(N_EDGES + 255) / 256, 256, 0, stream>>>(ridx, cursor, eord);

  const int eblocks = (N_EDGES + 159) / 160;  // 3125
  const int nblocks = (N_NODES + 127) / 128;  // 782
  edge_kernel<<<eblocks, 640, 73728, stream>>>(xb, edge_attr, eidx, wimg,
                                               eb1, eb2, eb3, eg, ebt,
                                               out_e, enew);
  node_kernel<<<nblocks, 512, 0, stream>>>(xb, x, enew, offs, eord, wimg,
                                           nb1, nb2, nb3, ng, nbt, out_x);
}

// Round 10
// 455.754 us; speedup vs baseline: 2.1879x; 1.1852x over previous
//
#include <hip/hip_runtime.h>

#define N_NODES 100000
#define N_EDGES 500000
#define H 128
#define EPS 1e-5f

typedef __attribute__((ext_vector_type(8))) short bf16x8;
typedef __attribute__((ext_vector_type(4))) float f32x4;

__device__ __forceinline__ unsigned short f2bf(float f) {
  unsigned int u = __builtin_bit_cast(unsigned int, f);
  u += 0x7FFFu + ((u >> 16) & 1u);
  return (unsigned short)(u >> 16);
}
__device__ __forceinline__ float bf2f(unsigned short u) {
  return __builtin_bit_cast(float, (unsigned)u << 16);
}

// XOR-swizzled LDS layout for [R x 128] bf16 tiles.
// (r,k) -> ushort idx r*128 + (k ^ ((r&7)<<3)); 16B chunks stay intact.
__device__ __forceinline__ int swz(int r, int k) {
  return r * 128 + (k ^ ((r & 7) << 3));
}

union PK8 { unsigned short u[8]; uint4 q; };

#define GLDS16(g, l)                                                        \
  __builtin_amdgcn_global_load_lds(                                         \
      (const __attribute__((address_space(1))) void*)(g),                   \
      (__attribute__((address_space(3))) void*)(l), 16, 0, 0)

// Copy a 32KB pre-swizzled weight image into LDS (512 threads x 16B x 4).
__device__ __forceinline__ void stage_w512(unsigned short* dst,
                                           const unsigned short* img) {
  const int t = threadIdx.x;
  #pragma unroll
  for (int j = 0; j < 4; ++j)
    GLDS16((const char*)img + j * 8192 + t * 16, (char*)dst + j * 8192 + t * 16);
}

// acc[8] += A(regs)[16 x 128] @ W(LDS)[128 -> 128]
__device__ __forceinline__ void gemm_regA(const bf16x8 a[4], const unsigned short* Wb,
                                          int m0, int kq, f32x4 acc[8]) {
  #pragma unroll
  for (int kk = 0; kk < 4; ++kk) {
    const int k0 = kk * 32 + kq * 8;
    #pragma unroll
    for (int tc = 0; tc < 8; ++tc) {
      bf16x8 b = *(const bf16x8*)&Wb[swz(tc * 16 + m0, k0)];
      acc[tc] = __builtin_amdgcn_mfma_f32_16x16x32_bf16(a[kk], b, acc[tc], 0, 0, 0);
    }
  }
}

// acc[8] += A(LDS rows wrow..wrow+16) @ W(LDS)
__device__ __forceinline__ void gemm_ldsA(const unsigned short* Hb, int wrow,
                                          const unsigned short* Wb,
                                          int m0, int kq, f32x4 acc[8]) {
  #pragma unroll
  for (int kk = 0; kk < 4; ++kk) {
    const int k0 = kk * 32 + kq * 8;
    bf16x8 a = *(const bf16x8*)&Hb[swz(wrow + m0, k0)];
    #pragma unroll
    for (int tc = 0; tc < 8; ++tc) {
      bf16x8 b = *(const bf16x8*)&Wb[swz(tc * 16 + m0, k0)];
      acc[tc] = __builtin_amdgcn_mfma_f32_16x16x32_bf16(a, b, acc[tc], 0, 0, 0);
    }
  }
}

__device__ __forceinline__ void zero_acc(f32x4 acc[8]) {
  #pragma unroll
  for (int b = 0; b < 8; ++b) acc[b] = (f32x4){0.f, 0.f, 0.f, 0.f};
}

// C-layout: col = tc*16 + (lane&15), row(within wave tile) = kq*4 + i
__device__ __forceinline__ void write_h(unsigned short* Hb, const f32x4 acc[8],
                                        const float* __restrict__ bias,
                                        int wrow, int m0, int kq) {
  #pragma unroll
  for (int tc = 0; tc < 8; ++tc) {
    const int col = tc * 16 + m0;
    const float b = bias[col];
    #pragma unroll
    for (int i = 0; i < 4; ++i)
      Hb[swz(wrow + kq * 4 + i, col)] = f2bf(fmaxf(acc[tc][i] + b, 0.0f));
  }
}

// relu only (bias already folded upstream)
__device__ __forceinline__ void write_h0(unsigned short* Hb, const f32x4 acc[8],
                                         int wrow, int m0, int kq) {
  #pragma unroll
  for (int tc = 0; tc < 8; ++tc) {
    const int col = tc * 16 + m0;
    #pragma unroll
    for (int i = 0; i < 4; ++i)
      Hb[swz(wrow + kq * 4 + i, col)] = f2bf(fmaxf(acc[tc][i], 0.0f));
  }
}

__device__ __forceinline__ void ln4(const f32x4 acc[8], float mu[4], float rv[4]) {
  float s[4] = {0, 0, 0, 0}, ss[4] = {0, 0, 0, 0};
  #pragma unroll
  for (int tc = 0; tc < 8; ++tc)
    #pragma unroll
    for (int i = 0; i < 4; ++i) {
      const float v = acc[tc][i];
      s[i] += v;
      ss[i] += v * v;
    }
  #pragma unroll
  for (int off = 1; off < 16; off <<= 1)
    #pragma unroll
    for (int i = 0; i < 4; ++i) {
      s[i] += __shfl_xor(s[i], off);
      ss[i] += __shfl_xor(ss[i], off);
    }
  #pragma unroll
  for (int i = 0; i < 4; ++i) {
    const float m = s[i] * (1.0f / 128.0f);
    const float var = ss[i] * (1.0f / 128.0f) - m * m;
    mu[i] = m;
    rv[i] = rsqrtf(var + EPS);
  }
}

// ---------------- prep kernels ----------------

__global__ void xprep_kernel(const float* __restrict__ x,
                             unsigned short* __restrict__ xb) {
  const long i = (long)blockIdx.x * 256 + threadIdx.x;
  const long base = i * 8;
  if (base < (long)N_NODES * H) {
    float4 v0 = *(const float4*)(x + base);
    float4 v1 = *(const float4*)(x + base + 4);
    PK8 pk;
    pk.u[0] = f2bf(v0.x); pk.u[1] = f2bf(v0.y);
    pk.u[2] = f2bf(v0.z); pk.u[3] = f2bf(v0.w);
    pk.u[4] = f2bf(v1.x); pk.u[5] = f2bf(v1.y);
    pk.u[6] = f2bf(v1.z); pk.u[7] = f2bf(v1.w);
    *(uint4*)(xb + base) = pk.q;
  }
}

struct WSrc { const float* p[9]; };

// Pre-swizzled LDS image: wimg[m*16384 + swz(n,k)] = W_m[k][n] (bf16)
__global__ void wprep_kernel(WSrc wsrc, unsigned short* __restrict__ wimg) {
  const int id = blockIdx.x * 256 + threadIdx.x;  // 9*16384
  const int m = id >> 14;
  const int r = id & 16383;
  const int n = r & 127;
  const int k = r >> 7;
  wimg[m * 16384 + swz(n, k)] = f2bf(wsrc.p[m][k * 128 + n]);
}

// ---------------- px precompute: pxs = x@eW1a+eb1, pxr = x@eW1b ----------------
// stored PERMUTED: px[node][m0*8+tc] = value for feature col tc*16+m0.

__global__ __launch_bounds__(512, 2) void px_kernel(
    const float* __restrict__ x, const unsigned short* __restrict__ wimg,
    const float* __restrict__ eb1,
    unsigned short* __restrict__ pxs, unsigned short* __restrict__ pxr) {
  __shared__ unsigned short smem[2 * 16384];  // eW1a | eW1b (64KB)
  const int t = threadIdx.x;
  #pragma unroll
  for (int j = 0; j < 8; ++j)
    GLDS16((const char*)wimg + j * 8192 + t * 16, (char*)smem + j * 8192 + t * 16);
  __syncthreads();

  const int lane = t & 63;
  const int wtile = (t >> 6) * 16;
  const int m0 = lane & 15;
  const int kq = lane >> 4;
  const long n0 = (long)blockIdx.x * 128;

  long an = n0 + wtile + m0;
  if (an > N_NODES - 1) an = N_NODES - 1;
  const float* px_ = x + an * H + kq * 8;
  bf16x8 aX[4];
  #pragma unroll
  for (int kk = 0; kk < 4; ++kk) {
    float4 v0 = *(const float4*)(px_ + kk * 32);
    float4 v1 = *(const float4*)(px_ + kk * 32 + 4);
    PK8 pk;
    pk.u[0] = f2bf(v0.x); pk.u[1] = f2bf(v0.y);
    pk.u[2] = f2bf(v0.z); pk.u[3] = f2bf(v0.w);
    pk.u[4] = f2bf(v1.x); pk.u[5] = f2bf(v1.y);
    pk.u[6] = f2bf(v1.z); pk.u[7] = f2bf(v1.w);
    aX[kk] = __builtin_bit_cast(bf16x8, pk.q);
  }
  const long cbn = n0 + wtile + kq * 4;

  f32x4 acc[8];
  float bv[8];
  // pxs = x @ eW1a + eb1
  zero_acc(acc);
  gemm_regA(aX, smem, m0, kq, acc);
  #pragma unroll
  for (int tc = 0; tc < 8; ++tc) bv[tc] = eb1[tc * 16 + m0];
  #pragma unroll
  for (int i = 0; i < 4; ++i) {
    const long nn = cbn + i;
    if (nn < N_NODES) {
      PK8 pk;
      #pragma unroll
      for (int tc = 0; tc < 8; ++tc) pk.u[tc] = f2bf(acc[tc][i] + bv[tc]);
      *(uint4*)(pxs + nn * H + m0 * 8) = pk.q;
    }
  }
  // pxr = x @ eW1b
  zero_acc(acc);
  gemm_regA(aX, smem + 16384, m0, kq, acc);
  #pragma unroll
  for (int i = 0; i < 4; ++i) {
    const long nn = cbn + i;
    if (nn < N_NODES) {
      PK8 pk;
      #pragma unroll
      for (int tc = 0; tc < 8; ++tc) pk.u[tc] = f2bf(acc[tc][i]);
      *(uint4*)(pxr + nn * H + m0 * 8) = pk.q;
    }
  }
}

// ---------------- CSR build ----------------

__global__ void hist_kernel(const int* __restrict__ ridx, unsigned* __restrict__ cnt) {
  const int e = blockIdx.x * 256 + threadIdx.x;
  if (e < N_EDGES) atomicAdd(&cnt[ridx[e]], 1u);
}

__global__ void scan1_kernel(const unsigned* __restrict__ cnt,
                             unsigned* __restrict__ offs,
                             unsigned* __restrict__ part) {
  __shared__ unsigned sh[256];
  const int t = threadIdx.x;
  const int base = blockIdx.x * 1024 + t * 4;
  unsigned v[4];
  #pragma unroll
  for (int i = 0; i < 4; ++i) v[i] = (base + i < N_NODES) ? cnt[base + i] : 0u;
  unsigned pre[4];
  pre[0] = 0; pre[1] = v[0]; pre[2] = v[0] + v[1]; pre[3] = pre[2] + v[2];
  const unsigned tot = pre[3] + v[3];
  sh[t] = tot;
  __syncthreads();
  for (int d = 1; d < 256; d <<= 1) {
    const unsigned u_ = (t >= d) ? sh[t - d] : 0u;
    __syncthreads();
    sh[t] += u_;
    __syncthreads();
  }
  const unsigned excl = sh[t] - tot;
  #pragma unroll
  for (int i = 0; i < 4; ++i)
    if (base + i < N_NODES) offs[base + i] = excl + pre[i];
  if (t == 255) part[blockIdx.x] = sh[255];
}

__global__ void scan2_kernel(unsigned* __restrict__ part, int n) {
  __shared__ unsigned sh[128];
  const int t = threadIdx.x;
  const unsigned v = (t < n) ? part[t] : 0u;
  sh[t] = v;
  __syncthreads();
  for (int d = 1; d < 128; d <<= 1) {
    const unsigned u_ = (t >= d) ? sh[t - d] : 0u;
    __syncthreads();
    sh[t] += u_;
    __syncthreads();
  }
  if (t < n) part[t] = sh[t] - v;
}

__global__ void scan3_kernel(unsigned* __restrict__ offs,
                             const unsigned* __restrict__ part,
                             unsigned* __restrict__ cursor) {
  const int i = blockIdx.x * 256 + threadIdx.x;
  if (i < N_NODES) {
    const unsigned o = offs[i] + part[i >> 10];
    offs[i] = o;
    cursor[i] = o;
  }
  if (i == 0) offs[N_NODES] = N_EDGES;
}

__global__ void scatter_kernel(const int* __restrict__ ridx,
                               unsigned* __restrict__ cursor,
                               unsigned* __restrict__ eord) {
  const int e = blockIdx.x * 256 + threadIdx.x;
  if (e < N_EDGES) {
    const unsigned p = atomicAdd(&cursor[ridx[e]], 1u);
    eord[p] = (unsigned)e;
  }
}

// ---------------- main kernels ----------------
// Edge: round-4 skeleton (512 thr, BM=128, 64KB static LDS, 2 blk/CU) with
// layer-1 x-gather GEMMs replaced by px gathers landing directly in C-layout.

__global__ __launch_bounds__(512, 4) void edge_kernel(
    const float* __restrict__ edge_attr, const int* __restrict__ eidx,
    const unsigned short* __restrict__ wimg,
    const unsigned short* __restrict__ pxs, const unsigned short* __restrict__ pxr,
    const float* __restrict__ eb2, const float* __restrict__ eb3,
    const float* __restrict__ eg, const float* __restrict__ ebeta,
    float* __restrict__ out_e, unsigned short* __restrict__ enew) {
  __shared__ unsigned short Wbuf[128 * 128];
  __shared__ unsigned short Hbuf[128 * 128];

  const int t = threadIdx.x;
  const int lane = t & 63;
  const int wave = t >> 6;
  const int wrow = wave * 16;
  const int m0 = lane & 15;
  const int kq = lane >> 4;
  const long e0 = (long)blockIdx.x * 128;
  const int* sidx = eidx;
  const int* ridx = eidx + N_EDGES;

  stage_w512(Wbuf, wimg + 2L * 16384);  // W1c (edge_attr weight)

  // px gathers for this lane's 4 C-rows (C-layout direct)
  const long cb = e0 + wrow + kq * 4;
  const long cbl = cb > (long)(N_EDGES - 4) ? (long)(N_EDGES - 4) : cb;
  int4 s4 = *(const int4*)&sidx[cbl];
  int4 r4 = *(const int4*)&ridx[cbl];
  const int* sp = (const int*)&s4;
  const int* rp = (const int*)&r4;
  uint4 qs[4], qr[4];
  #pragma unroll
  for (int i = 0; i < 4; ++i) {
    qs[i] = *(const uint4*)(pxs + (long)sp[i] * H + m0 * 8);
    qr[i] = *(const uint4*)(pxr + (long)rp[i] * H + m0 * 8);
  }

  // edge_attr A-fragments (f32 -> bf16)
  long erow = e0 + wrow + m0;
  if (erow > N_EDGES - 1) erow = N_EDGES - 1;
  bf16x8 aE[4];
  {
    const float* pe = edge_attr + erow * (long)H + kq * 8;
    #pragma unroll
    for (int kk = 0; kk < 4; ++kk) {
      float4 v0 = *(const float4*)(pe + kk * 32);
      float4 v1 = *(const float4*)(pe + kk * 32 + 4);
      PK8 pk;
      pk.u[0] = f2bf(v0.x); pk.u[1] = f2bf(v0.y);
      pk.u[2] = f2bf(v0.z); pk.u[3] = f2bf(v0.w);
      pk.u[4] = f2bf(v1.x); pk.u[5] = f2bf(v1.y);
      pk.u[6] = f2bf(v1.z); pk.u[7] = f2bf(v1.w);
      aE[kk] = __builtin_bit_cast(bf16x8, pk.q);
    }
  }

  f32x4 acc[8];
  zero_acc(acc);

  __syncthreads();  // W1c staged
  gemm_regA(aE, Wbuf, m0, kq, acc);
  // add px_s + px_r (eb1 folded into pxs)
  #pragma unroll
  for (int i = 0; i < 4; ++i) {
    const unsigned short* us = (const unsigned short*)&qs[i];
    const unsigned short* ur = (const unsigned short*)&qr[i];
    #pragma unroll
    for (int tc = 0; tc < 8; ++tc)
      acc[tc][i] += bf2f(us[tc]) + bf2f(ur[tc]);
  }

  __syncthreads();  // Wbuf (W1c) consumed by all waves
  stage_w512(Wbuf, wimg + 3L * 16384);  // W2
  write_h0(Hbuf, acc, wrow, m0, kq);    // h1 (wave-local rows)
  zero_acc(acc);
  __syncthreads();
  gemm_ldsA(Hbuf, wrow, Wbuf, m0, kq, acc);

  __syncthreads();
  stage_w512(Wbuf, wimg + 4L * 16384);  // W3
  write_h(Hbuf, acc, eb2, wrow, m0, kq);  // h2
  zero_acc(acc);
  __syncthreads();
  gemm_ldsA(Hbuf, wrow, Wbuf, m0, kq, acc);

  // ---- epilogue: +b3, LN ----
  float gm[8], bt[8];
  #pragma unroll
  for (int tc = 0; tc < 8; ++tc) {
    const int col = tc * 16 + m0;
    const float b3 = eb3[col];
    gm[tc] = eg[col];
    bt[tc] = ebeta[col];
    #pragma unroll
    for (int i = 0; i < 4; ++i) acc[tc][i] += b3;
  }
  float mu[4], rv[4];
  ln4(acc, mu, rv);

  __syncthreads();  // Hbuf (h2) consumed by all waves
  #pragma unroll
  for (int tc = 0; tc < 8; ++tc) {
    const int col = tc * 16 + m0;
    #pragma unroll
    for (int i = 0; i < 4; ++i) {
      const float y = (acc[tc][i] - mu[i]) * rv[i] * gm[tc] + bt[tc];
      Hbuf[swz(wrow + kq * 4 + i, col)] = f2bf(y);
    }
  }
  __syncthreads();

  // coalesced stores: 4 threads per row, 32 cols each
  {
    const int r = t >> 2;
    const int c0 = (t & 3) * 32;
    const long e = e0 + r;
    if (e < N_EDGES) {
      const float* ea = edge_attr + e * (long)H + c0;
      float* oe = out_e + e * (long)H + c0;
      unsigned short* en = enew + e * (long)H + c0;
      #pragma unroll
      for (int c2 = 0; c2 < 4; ++c2) {
        uint4 qv = *(const uint4*)&Hbuf[swz(r, c0 + c2 * 8)];
        *(uint4*)(en + c2 * 8) = qv;
        const unsigned short* pu = (const unsigned short*)&qv;
        float4 a0 = *(const float4*)(ea + c2 * 8);
        float4 a1 = *(const float4*)(ea + c2 * 8 + 4);
        float4 o0, o1;
        o0.x = a0.x + bf2f(pu[0]); o0.y = a0.y + bf2f(pu[1]);
        o0.z = a0.z + bf2f(pu[2]); o0.w = a0.w + bf2f(pu[3]);
        o1.x = a1.x + bf2f(pu[4]); o1.y = a1.y + bf2f(pu[5]);
        o1.z = a1.z + bf2f(pu[6]); o1.w = a1.w + bf2f(pu[7]);
        *(float4*)(oe + c2 * 8) = o0;
        *(float4*)(oe + c2 * 8 + 4) = o1;
      }
    }
  }
}

__global__ __launch_bounds__(512, 4) void node_kernel(
    const unsigned short* __restrict__ xb, const float* __restrict__ x,
    const unsigned short* __restrict__ enew,
    const unsigned* __restrict__ offs, const unsigned* __restrict__ eord,
    const unsigned short* __restrict__ wimg,
    const float* __restrict__ nb1, const float* __restrict__ nb2,
    const float* __restrict__ nb3,
    const float* __restrict__ ng, const float* __restrict__ nbeta,
    float* __restrict__ out_x) {
  __shared__ unsigned short Wbuf[128 * 128];
  __shared__ unsigned short Hbuf[128 * 128];

  const int t = threadIdx.x;
  const int lane = t & 63;
  const int wave = t >> 6;
  const int wrow = wave * 16;
  const int m0 = lane & 15;
  const int kq = lane >> 4;
  const long n0 = (long)blockIdx.x * 128;

  stage_w512(Wbuf, wimg + 5L * 16384);  // nW1a

  // x fragments to registers
  long nrow = n0 + wrow + m0;
  if (nrow > N_NODES - 1) nrow = N_NODES - 1;
  bf16x8 aX[4];
  {
    const unsigned short* px = xb + nrow * H + kq * 8;
    #pragma unroll
    for (int kk = 0; kk < 4; ++kk) aX[kk] = *(const bf16x8*)(px + kk * 32);
  }

  // CSR gather-sum: thread t owns (row t>>2, col quarter t&3)
  float av[32];
  #pragma unroll
  for (int i = 0; i < 32; ++i) av[i] = 0.f;
  {
    const long sn = n0 + (t >> 2);
    if (sn < N_NODES) {
      const unsigned o0 = offs[sn], o1 = offs[sn + 1];
      const int c0 = (t & 3) * 32;
      for (unsigned u_ = o0; u_ < o1; ++u_) {
        const unsigned short* er = enew + (long)eord[u_] * H + c0;
        #pragma unroll
        for (int c2 = 0; c2 < 4; ++c2) {
          uint4 qv = *(const uint4*)(er + c2 * 8);
          const unsigned short* pu = (const unsigned short*)&qv;
          #pragma unroll
          for (int j = 0; j < 8; ++j) av[c2 * 8 + j] += bf2f(pu[j]);
        }
      }
    }
  }

  f32x4 acc[8];
  zero_acc(acc);

  __syncthreads();  // Wbuf staged
  gemm_regA(aX, Wbuf, m0, kq, acc);
  __syncthreads();
  stage_w512(Wbuf, wimg + 6L * 16384);  // nW1b
  // av -> Hbuf (bf16, swizzled)
  {
    const int r = t >> 2;
    const int c0 = (t & 3) * 32;
    #pragma unroll
    for (int c2 = 0; c2 < 4; ++c2) {
      PK8 pk;
      #pragma unroll
      for (int j = 0; j < 8; ++j) pk.u[j] = f2bf(av[c2 * 8 + j]);
      *(uint4*)&Hbuf[swz(r, c0 + c2 * 8)] = pk.q;
    }
  }
  __syncthreads();
  gemm_ldsA(Hbuf, wrow, Wbuf, m0, kq, acc);  // acc += agg @ nW1b

  __syncthreads();
  stage_w512(Wbuf, wimg + 7L * 16384);  // nW2
  write_h(Hbuf, acc, nb1, wrow, m0, kq);
  zero_acc(acc);
  __syncthreads();
  gemm_ldsA(Hbuf, wrow, Wbuf, m0, kq, acc);

  __syncthreads();
  stage_w512(Wbuf, wimg + 8L * 16384);  // nW3
  write_h(Hbuf, acc, nb2, wrow, m0, kq);
  zero_acc(acc);
  __syncthreads();
  gemm_ldsA(Hbuf, wrow, Wbuf, m0, kq, acc);

  // epilogue
  float gm[8], bt[8];
  #pragma unroll
  for (int tc = 0; tc < 8; ++tc) {
    const int col = tc * 16 + m0;
    const float b3 = nb3[col];
    gm[tc] = ng[col];
    bt[tc] = nbeta[col];
    #pragma unroll
    for (int i = 0; i < 4; ++i) acc[tc][i] += b3;
  }
  float mu[4], rv[4];
  ln4(acc, mu, rv);

  __syncthreads();
  #pragma unroll
  for (int tc = 0; tc < 8; ++tc) {
    const int col = tc * 16 + m0;
    #pragma unroll
    for (int i = 0; i < 4; ++i) {
      const float y = (acc[tc][i] - mu[i]) * rv[i] * gm[tc] + bt[tc];
      Hbuf[swz(wrow + kq * 4 + i, col)] = f2bf(y);
    }
  }
  __syncthreads();

  {
    const int r = t >> 2;
    const int c0 = (t & 3) * 32;
    const long n = n0 + r;
    if (n < N_NODES) {
      const float* xr = x + n * (long)H + c0;
      float* ox = out_x + n * (long)H + c0;
      #pragma unroll
      for (int c2 = 0; c2 < 4; ++c2) {
        uint4 qv = *(const uint4*)&Hbuf[swz(r, c0 + c2 * 8)];
        const unsigned short* pu = (const unsigned short*)&qv;
        float4 a0 = *(const float4*)(xr + c2 * 8);
        float4 a1 = *(const float4*)(xr + c2 * 8 + 4);
        float4 o0, o1;
        o0.x = a0.x + bf2f(pu[0]); o0.y = a0.y + bf2f(pu[1]);
        o0.z = a0.z + bf2f(pu[2]); o0.w = a0.w + bf2f(pu[3]);
        o1.x = a1.x + bf2f(pu[4]); o1.y = a1.y + bf2f(pu[5]);
        o1.z = a1.z + bf2f(pu[6]); o1.w = a1.w + bf2f(pu[7]);
        *(float4*)(ox + c2 * 8) = o0;
        *(float4*)(ox + c2 * 8 + 4) = o1;
      }
    }
  }
}

extern "C" void kernel_launch(void* const* d_in, const int* in_sizes, int n_in,
                              void* d_out, int out_size, void* d_ws, size_t ws_size,
                              hipStream_t stream) {
  (void)in_sizes; (void)n_in; (void)out_size; (void)ws_size;
  const float* x         = (const float*)d_in[0];
  const float* edge_attr = (const float*)d_in[1];
  const int*   eidx      = (const int*)d_in[2];
  const float* eW1 = (const float*)d_in[3];
  const float* eb1 = (const float*)d_in[4];
  const float* eW2 = (const float*)d_in[5];
  const float* eb2 = (const float*)d_in[6];
  const float* eW3 = (const float*)d_in[7];
  const float* eb3 = (const float*)d_in[8];
  const float* eg  = (const float*)d_in[9];
  const float* ebt = (const float*)d_in[10];
  const float* nW1 = (const float*)d_in[11];
  const float* nb1 = (const float*)d_in[12];
  const float* nW2 = (const float*)d_in[13];
  const float* nb2 = (const float*)d_in[14];
  const float* nW3 = (const float*)d_in[15];
  const float* nb3 = (const float*)d_in[16];
  const float* ng  = (const float*)d_in[17];
  const float* nbt = (const float*)d_in[18];

  float* out_x = (float*)d_out;                        // N_NODES*H
  float* out_e = (float*)d_out + (size_t)N_NODES * H;  // N_EDGES*H

  // ws layout (bytes)
  char* w = (char*)d_ws;
  unsigned short* enew = (unsigned short*)(w + 0);            // 128,000,000
  unsigned short* xb   = (unsigned short*)(w + 128000000);    //  25,600,000
  unsigned short* pxs  = (unsigned short*)(w + 153600000);    //  25,600,000
  unsigned short* pxr  = (unsigned short*)(w + 179200000);    //  25,600,000
  unsigned short* wimg = (unsigned short*)(w + 204800000);    //     294,912
  unsigned* offs   = (unsigned*)(w + 205094912);              //     400,128
  unsigned* cnt    = (unsigned*)(w + 205495040);              //     400,128
  unsigned* cursor = (unsigned*)(w + 205895168);              //     400,128
  unsigned* part   = (unsigned*)(w + 206295296);              //       1,024
  unsigned* eord   = (unsigned*)(w + 206296320);              //   2,000,000
  // total ~208.3 MB

  const int* ridx = eidx + N_EDGES;

  hipMemsetAsync(cnt, 0, (size_t)N_NODES * sizeof(unsigned), stream);

  WSrc wsrc;
  wsrc.p[0] = eW1;                 // eW1a (senders)    -> px
  wsrc.p[1] = eW1 + 16384;         // eW1b (receivers)  -> px
  wsrc.p[2] = eW1 + 32768;         // eW1c (edge_attr)  -> edge
  wsrc.p[3] = eW2;                 //                    -> edge
  wsrc.p[4] = eW3;                 //                    -> edge
  wsrc.p[5] = nW1;                 // nW1a (x)           -> node
  wsrc.p[6] = nW1 + 16384;         // nW1b (agg)         -> node
  wsrc.p[7] = nW2;                 //                    -> node
  wsrc.p[8] = nW3;                 //                    -> node

  xprep_kernel<<<(N_NODES * H / 8 + 255) / 256, 256, 0, stream>>>(x, xb);
  wprep_kernel<<<576, 256, 0, stream>>>(wsrc, wimg);

  px_kernel<<<(N_NODES + 127) / 128, 512, 0, stream>>>(x, wimg, eb1, pxs, pxr);

  hist_kernel<<<(N_EDGES + 255) / 256, 256, 0, stream>>>(ridx, cnt);
  scan1_kernel<<<(N_NODES + 1023) / 1024, 256, 0, stream>>>(cnt, offs, part);
  scan2_kernel<<<1, 128, 0, stream>>>(part, (N_NODES + 1023) / 1024);
  scan3_kernel<<<(N_NODES + 255) / 256, 256, 0, stream>>>(offs, part, cursor);
  scatter_kernel<<<(N_EDGES + 255) / 256, 256, 0, stream>>>(ridx, cursor, eord);

  const int eblocks = (N_EDGES + 127) / 128;  // 3907
  const int nblocks = (N_NODES + 127) / 128;  // 782
  edge_kernel<<<eblocks, 512, 0, stream>>>(edge_attr, eidx, wimg, pxs, pxr,
                                           eb2, eb3, eg, ebt, out_e, enew);
  node_kernel<<<nblocks, 512, 0, stream>>>(xb, x, enew, offs, eord, wimg,
                                           nb1, nb2, nb3, ng, nbt, out_x);
}